// Round 8
// baseline (8915.832 us; speedup 1.0000x reference)
//
#include <hip/hip_runtime.h>

// RVQ encoder — bit-exact emulation of the harness numpy reference under the
// BLAS hypothesis: einsums evaluated via OpenBLAS sgemm (k-serial FMA chains,
// Q=384 panel splits), np.sum via scalar pairwise 8-accumulator blocks.
//  * E(d2) (K=128):   acc = fmaf(r[k], c[k], acc), k ascending, single chain
//  * x-proj (K=512):  (chain(0:384) + chain(384:512)) + in_b
//  * sem-bias(K=4096):((ch0+ch1)+...)+ch10 (10x384+256) + sem_b
//  * A,C:             numpy pairwise 8-acc, ((s0+s1)+(s2+s3))+((s4+s5)+(s6+s7))
//  * d2 = (A - 2f*E) + C ; argmin = first minimum (lowest index on ties)
//
// R8 change: route the codebook stream through the VECTOR memory path.
// R7 evidence: VGPR=40 (codebook float4s not in VGPRs) + SGPR=112 => compiler
// scalarized the wave-uniform codebook loads into s_load through the
// low-BW scalar cache, gated by all-draining lgkmcnt(0) -> VALUBusy 38%.
// New scan: each lane handles 2 rows x 64 codes (pr=lane&31, ch=lane>>5;
// rows {pr, pr+32}, codes [wave*128+ch*64, +64)). Lane-dependent addresses
// force global_load_dwordx4 (L1 broadcast, vmcnt-counted waits); per kk,
// 8 loads + 2 ds_read feed 64 FMAs (2x the FMA:load ratio of R7).
// Exact numerics unchanged: per-code E is the same single k-ascending fmaf
// chain; per-row merge order stays ascending-code (wave asc, ch asc).
// launch_bounds(512,4) pins VGPR<=64 => 4 waves/SIMD retained.
//
// ws: biasg f32[10240] | x f32[4194304] | norms f32[32768] | part f64[512]
// d_out (f32): quantized[4194304] | indices-as-f32[1048576] | closs[1]

// ---- np-exact helpers --------------------------------------------------------

__device__ __forceinline__ float np_add_scaled(float r, float b) {
#pragma clang fp contract(off)
  float t = 0.1f * b;
  return r + t;
}

__device__ __forceinline__ float np_ste(float x, float q) {
#pragma clang fp contract(off)
  float t = q - x;
  return x + t;
}

// numpy pairwise 8-acc sum of squares over 128 elems read as float4[32]
__device__ __forceinline__ float np_A_from(const float4* __restrict__ r4p) {
  float A;
  {
#pragma clang fp contract(off)
    float4 u = r4p[0], v = r4p[1];
    float s0 = u.x * u.x, s1 = u.y * u.y, s2 = u.z * u.z, s3 = u.w * u.w;
    float s4 = v.x * v.x, s5 = v.y * v.y, s6 = v.z * v.z, s7 = v.w * v.w;
#pragma unroll
    for (int t = 1; t < 16; ++t) {
      u = r4p[2 * t]; v = r4p[2 * t + 1];
      s0 += u.x * u.x; s1 += u.y * u.y; s2 += u.z * u.z; s3 += u.w * u.w;
      s4 += v.x * v.x; s5 += v.y * v.y; s6 += v.z * v.z; s7 += v.w * v.w;
    }
    A = ((s0 + s1) + (s2 + s3)) + ((s4 + s5) + (s6 + s7));
  }
  return A;
}

// ---- A: per-code norms (np pairwise 8-acc, streaming) ------------------------
__global__ __launch_bounds__(256) void code_norms_np(const float* __restrict__ cb,
                                                     float* __restrict__ norms) {
  int i = blockIdx.x * 256 + threadIdx.x;            // k*1024+c
  norms[i] = np_A_from((const float4*)(cb + (size_t)i * 128));
}

// ---- B: x = af @ in_w^T + in_b via sgemm semantics (K=512 -> 384+128) --------
__global__ __launch_bounds__(256, 2) void xproj_blas(const float* __restrict__ af,
                                                     const float* __restrict__ in_w,
                                                     const float* __restrict__ in_b,
                                                     float* __restrict__ x) {
  int row = blockIdx.x * 256 + threadIdx.x;          // 0..32767
  const float* ar = af + (size_t)row * 512;
  for (int oc = 0; oc < 8; ++oc) {                   // 16 outputs per group
    float accA[16], accB[16];
#pragma unroll
    for (int o = 0; o < 16; ++o) { accA[o] = 0.f; accB[o] = 0.f; }
    for (int kc = 0; kc < 8; ++kc) {                 // 64-element k chunks
      float a[64];
      const float4* ap = (const float4*)(ar + kc * 64);
#pragma unroll
      for (int i = 0; i < 16; ++i) {
        float4 v = ap[i];
        a[4 * i] = v.x; a[4 * i + 1] = v.y; a[4 * i + 2] = v.z; a[4 * i + 3] = v.w;
      }
      if (kc < 6) {                                  // k = 0..383 -> panel A
#pragma unroll
        for (int o = 0; o < 16; ++o) {
          const float* wr = in_w + (size_t)(oc * 16 + o) * 512 + kc * 64;
          float acc = accA[o];
#pragma unroll
          for (int m = 0; m < 64; ++m) acc = fmaf(a[m], wr[m], acc);
          accA[o] = acc;
        }
      } else {                                       // k = 384..511 -> panel B
#pragma unroll
        for (int o = 0; o < 16; ++o) {
          const float* wr = in_w + (size_t)(oc * 16 + o) * 512 + kc * 64;
          float acc = accB[o];
#pragma unroll
          for (int m = 0; m < 64; ++m) acc = fmaf(a[m], wr[m], acc);
          accB[o] = acc;
        }
      }
    }
    {
#pragma clang fp contract(off)
#pragma unroll
      for (int o = 0; o < 16; ++o) {
        float E = accA[o] + accB[o];                 // panel junction add
        x[(size_t)row * 128 + oc * 16 + o] = E + in_b[oc * 16 + o];
      }
    }
  }
}

// ---- C: sem_bias via sgemm semantics (K=4096 -> 10x384 + 256 panels) ---------
__global__ __launch_bounds__(256) void sembias_blas(const float* __restrict__ sem_w,
                                                    const float* __restrict__ sem_b,
                                                    const float* __restrict__ ctx,
                                                    float* __restrict__ biasg) {
  int tid = blockIdx.x * 256 + threadIdx.x;          // 0..1279 = k*128+d
  if (tid >= 1280) return;
  int k = tid >> 7, d = tid & 127;
  const float* w = sem_w + (size_t)tid * 4096;
  float val[8];
  for (int j = 0; j < 11; ++j) {                     // sgemm k-panels
    int p0 = j * 384;
    int len = (j < 10) ? 384 : 256;                  // 10*384 + 256 = 4096
    float acc[8] = {0.f, 0.f, 0.f, 0.f, 0.f, 0.f, 0.f, 0.f};
    for (int i = 0; i < len; ++i) {
      float wv = w[p0 + i];
#pragma unroll
      for (int b = 0; b < 8; ++b)
        acc[b] = fmaf(wv, ctx[(size_t)b * 4096 + p0 + i], acc[b]);
    }
    {
#pragma clang fp contract(off)
      if (j == 0) {
#pragma unroll
        for (int b = 0; b < 8; ++b) val[b] = acc[b];
      } else {
#pragma unroll
        for (int b = 0; b < 8; ++b) val[b] = val[b] + acc[b];
      }
    }
  }
  {
#pragma clang fp contract(off)
#pragma unroll
    for (int b = 0; b < 8; ++b)
      biasg[((size_t)k * 8 + b) * 128 + d] = val[b] + sem_b[k * 128 + d];
  }
}

// ---- D: main 32-step loop — r in LDS, 2 rows x 64 codes per lane -------------
// 512 threads = 8 waves; 64 rows/WG. Lane l: pr=l&31, ch=l>>5; handles rows
// {pr, pr+32} over codes [wave*128 + ch*64, +64) in 8 blocks of 8.
// Cooperative phases (bias/subtract) use the (row=tid&63, seg=tid>>6)
// partition: each thread owns 16 dims of one row.
#define RSTRIDE 132                                   // 128 + 4 pad (16B-aligned)
__global__ __launch_bounds__(512, 4) void rvq_main(const float* __restrict__ cb,
                                                   const float* __restrict__ norms,
                                                   const float* __restrict__ biasg,
                                                   const float* __restrict__ x,
                                                   float* __restrict__ outIdx) {
  const int tid = threadIdx.x;
  const int lane = tid & 63;
  const int wave = __builtin_amdgcn_readfirstlane(tid >> 6);  // 0..7
  const int wg = blockIdx.x;                          // 0..511
  const int b = wg >> 6;

  __shared__ float rS[64 * RSTRIDE];                  // 33 KB
  __shared__ float biasS[10 * 128];
  __shared__ float candVa[8][64];                     // row pr candidates
  __shared__ int candIa[8][64];
  __shared__ float candVb[8][64];                     // row pr+32 candidates
  __shared__ int candIb[8][64];
  __shared__ int chosen[64];

  for (int t = tid; t < 10 * 128; t += 512) {
    biasS[t] = biasg[((size_t)(t >> 7) * 8 + b) * 128 + (t & 127)];
  }
  {
    const int r0 = tid & 63, seg = tid >> 6;          // 16 dims per thread
    const float4* xp = (const float4*)(x + (size_t)((wg << 6) + r0) * 128 + seg * 16);
    float4* rp = (float4*)(rS + r0 * RSTRIDE + seg * 16);
#pragma unroll
    for (int i = 0; i < 4; ++i) rp[i] = xp[i];
  }
  __syncthreads();

  const int pr = lane & 31;                           // row-pair base
  const int ch = lane >> 5;                           // code half within wave
  const int cstart = (wave << 7) + (ch << 6);         // 64 codes per lane
  const float4* r4pa = (const float4*)(rS + pr * RSTRIDE);
  const float4* r4pb = (const float4*)(rS + (pr + 32) * RSTRIDE);

  for (int k = 0; k < 32; ++k) {
    if (k < 10) {                                     // bias add, np order
      const int r0 = tid & 63, seg = tid >> 6;
      float* rp = rS + r0 * RSTRIDE + seg * 16;
      const float* bp = biasS + (k << 7) + seg * 16;
#pragma unroll
      for (int d = 0; d < 16; ++d) rp[d] = np_add_scaled(rp[d], bp[d]);
      __syncthreads();
    }
    // A for both rows (np pairwise 8-acc; redundant across waves, cheap)
    float Aa = np_A_from(r4pa);
    float Ab = np_A_from(r4pb);

    const float* cbk = cb + ((size_t)k << 17);
    const float* nk = norms + (k << 10);
    float bestVa = 3.4e38f, bestVb = 3.4e38f;
    int bestIa = cstart, bestIb = cstart;
    for (int blk = 0; blk < 8; ++blk) {               // 8 codes per block
      const int cbase = cstart + (blk << 3);
      const float4* c4 = (const float4*)(cbk + ((size_t)cbase << 7));
      float Ea0 = 0.f, Ea1 = 0.f, Ea2 = 0.f, Ea3 = 0.f;
      float Ea4 = 0.f, Ea5 = 0.f, Ea6 = 0.f, Ea7 = 0.f;
      float Eb0 = 0.f, Eb1 = 0.f, Eb2 = 0.f, Eb3 = 0.f;
      float Eb4 = 0.f, Eb5 = 0.f, Eb6 = 0.f, Eb7 = 0.f;
      for (int kk = 0; kk < 32; ++kk) {               // k4 chunks, ascending
        float4 ra = r4pa[kk];
        float4 rb = r4pb[kk];
        float4 q0 = c4[kk];                           // code j at +j*32 float4s
        float4 q1 = c4[kk + 32];
        float4 q2 = c4[kk + 64];
        float4 q3 = c4[kk + 96];
        float4 q4 = c4[kk + 128];
        float4 q5 = c4[kk + 160];
        float4 q6 = c4[kk + 192];
        float4 q7 = c4[kk + 224];
        Ea0 = fmaf(ra.x, q0.x, Ea0); Ea0 = fmaf(ra.y, q0.y, Ea0);
        Ea0 = fmaf(ra.z, q0.z, Ea0); Ea0 = fmaf(ra.w, q0.w, Ea0);
        Eb0 = fmaf(rb.x, q0.x, Eb0); Eb0 = fmaf(rb.y, q0.y, Eb0);
        Eb0 = fmaf(rb.z, q0.z, Eb0); Eb0 = fmaf(rb.w, q0.w, Eb0);
        Ea1 = fmaf(ra.x, q1.x, Ea1); Ea1 = fmaf(ra.y, q1.y, Ea1);
        Ea1 = fmaf(ra.z, q1.z, Ea1); Ea1 = fmaf(ra.w, q1.w, Ea1);
        Eb1 = fmaf(rb.x, q1.x, Eb1); Eb1 = fmaf(rb.y, q1.y, Eb1);
        Eb1 = fmaf(rb.z, q1.z, Eb1); Eb1 = fmaf(rb.w, q1.w, Eb1);
        Ea2 = fmaf(ra.x, q2.x, Ea2); Ea2 = fmaf(ra.y, q2.y, Ea2);
        Ea2 = fmaf(ra.z, q2.z, Ea2); Ea2 = fmaf(ra.w, q2.w, Ea2);
        Eb2 = fmaf(rb.x, q2.x, Eb2); Eb2 = fmaf(rb.y, q2.y, Eb2);
        Eb2 = fmaf(rb.z, q2.z, Eb2); Eb2 = fmaf(rb.w, q2.w, Eb2);
        Ea3 = fmaf(ra.x, q3.x, Ea3); Ea3 = fmaf(ra.y, q3.y, Ea3);
        Ea3 = fmaf(ra.z, q3.z, Ea3); Ea3 = fmaf(ra.w, q3.w, Ea3);
        Eb3 = fmaf(rb.x, q3.x, Eb3); Eb3 = fmaf(rb.y, q3.y, Eb3);
        Eb3 = fmaf(rb.z, q3.z, Eb3); Eb3 = fmaf(rb.w, q3.w, Eb3);
        Ea4 = fmaf(ra.x, q4.x, Ea4); Ea4 = fmaf(ra.y, q4.y, Ea4);
        Ea4 = fmaf(ra.z, q4.z, Ea4); Ea4 = fmaf(ra.w, q4.w, Ea4);
        Eb4 = fmaf(rb.x, q4.x, Eb4); Eb4 = fmaf(rb.y, q4.y, Eb4);
        Eb4 = fmaf(rb.z, q4.z, Eb4); Eb4 = fmaf(rb.w, q4.w, Eb4);
        Ea5 = fmaf(ra.x, q5.x, Ea5); Ea5 = fmaf(ra.y, q5.y, Ea5);
        Ea5 = fmaf(ra.z, q5.z, Ea5); Ea5 = fmaf(ra.w, q5.w, Ea5);
        Eb5 = fmaf(rb.x, q5.x, Eb5); Eb5 = fmaf(rb.y, q5.y, Eb5);
        Eb5 = fmaf(rb.z, q5.z, Eb5); Eb5 = fmaf(rb.w, q5.w, Eb5);
        Ea6 = fmaf(ra.x, q6.x, Ea6); Ea6 = fmaf(ra.y, q6.y, Ea6);
        Ea6 = fmaf(ra.z, q6.z, Ea6); Ea6 = fmaf(ra.w, q6.w, Ea6);
        Eb6 = fmaf(rb.x, q6.x, Eb6); Eb6 = fmaf(rb.y, q6.y, Eb6);
        Eb6 = fmaf(rb.z, q6.z, Eb6); Eb6 = fmaf(rb.w, q6.w, Eb6);
        Ea7 = fmaf(ra.x, q7.x, Ea7); Ea7 = fmaf(ra.y, q7.y, Ea7);
        Ea7 = fmaf(ra.z, q7.z, Ea7); Ea7 = fmaf(ra.w, q7.w, Ea7);
        Eb7 = fmaf(rb.x, q7.x, Eb7); Eb7 = fmaf(rb.y, q7.y, Eb7);
        Eb7 = fmaf(rb.z, q7.z, Eb7); Eb7 = fmaf(rb.w, q7.w, Eb7);
      }
      {                                               // exact e, np_d2_blas form
#pragma clang fp contract(off)
        float e;
        e = (Aa - 2.0f * Ea0) + nk[cbase + 0];
        if (e < bestVa) { bestVa = e; bestIa = cbase + 0; }
        e = (Aa - 2.0f * Ea1) + nk[cbase + 1];
        if (e < bestVa) { bestVa = e; bestIa = cbase + 1; }
        e = (Aa - 2.0f * Ea2) + nk[cbase + 2];
        if (e < bestVa) { bestVa = e; bestIa = cbase + 2; }
        e = (Aa - 2.0f * Ea3) + nk[cbase + 3];
        if (e < bestVa) { bestVa = e; bestIa = cbase + 3; }
        e = (Aa - 2.0f * Ea4) + nk[cbase + 4];
        if (e < bestVa) { bestVa = e; bestIa = cbase + 4; }
        e = (Aa - 2.0f * Ea5) + nk[cbase + 5];
        if (e < bestVa) { bestVa = e; bestIa = cbase + 5; }
        e = (Aa - 2.0f * Ea6) + nk[cbase + 6];
        if (e < bestVa) { bestVa = e; bestIa = cbase + 6; }
        e = (Aa - 2.0f * Ea7) + nk[cbase + 7];
        if (e < bestVa) { bestVa = e; bestIa = cbase + 7; }
        e = (Ab - 2.0f * Eb0) + nk[cbase + 0];
        if (e < bestVb) { bestVb = e; bestIb = cbase + 0; }
        e = (Ab - 2.0f * Eb1) + nk[cbase + 1];
        if (e < bestVb) { bestVb = e; bestIb = cbase + 1; }
        e = (Ab - 2.0f * Eb2) + nk[cbase + 2];
        if (e < bestVb) { bestVb = e; bestIb = cbase + 2; }
        e = (Ab - 2.0f * Eb3) + nk[cbase + 3];
        if (e < bestVb) { bestVb = e; bestIb = cbase + 3; }
        e = (Ab - 2.0f * Eb4) + nk[cbase + 4];
        if (e < bestVb) { bestVb = e; bestIb = cbase + 4; }
        e = (Ab - 2.0f * Eb5) + nk[cbase + 5];
        if (e < bestVb) { bestVb = e; bestIb = cbase + 5; }
        e = (Ab - 2.0f * Eb6) + nk[cbase + 6];
        if (e < bestVb) { bestVb = e; bestIb = cbase + 6; }
        e = (Ab - 2.0f * Eb7) + nk[cbase + 7];
        if (e < bestVb) { bestVb = e; bestIb = cbase + 7; }
      }
    }
    candVa[wave][lane] = bestVa;
    candIa[wave][lane] = bestIa;
    candVb[wave][lane] = bestVb;
    candIb[wave][lane] = bestIb;
    __syncthreads();
    if (wave == 0) {                                  // merge for row = lane
      const int pr2 = lane & 31;
      const int slot = lane >> 5;                     // 0: row pr; 1: row pr+32
      float mv = 3.4e38f;
      int mi = 0;
#pragma unroll
      for (int w = 0; w < 8; ++w) {
#pragma unroll
        for (int c2 = 0; c2 < 2; ++c2) {              // ascending code order
          int src = (c2 << 5) + pr2;
          float v = slot ? candVb[w][src] : candVa[w][src];
          int ci = slot ? candIb[w][src] : candIa[w][src];
          if (v < mv || (v == mv && ci < mi)) { mv = v; mi = ci; }
        }
      }
      chosen[lane] = mi;
      outIdx[(k << 15) + (wg << 6) + lane] = (float)mi;
    }
    __syncthreads();
    {                                                 // subtract, exact single sub
      const int r0 = tid & 63, seg = tid >> 6;
      const float* q = cbk + ((size_t)chosen[r0] << 7) + seg * 16;
      float* rp = rS + r0 * RSTRIDE + seg * 16;
#pragma unroll
      for (int d = 0; d < 16; ++d) rp[d] = rp[d] - q[d];
    }
    __syncthreads();
  }
}

// ---- E: quantized (fp32 k-order accumulate + STE) + closs partials -----------
__global__ __launch_bounds__(256) void quant_closs(const float* __restrict__ cb,
                                                   const float* __restrict__ x,
                                                   const float* __restrict__ idxF,
                                                   float* __restrict__ outQ,
                                                   double* __restrict__ partials) {
  int gid = blockIdx.x * 256 + threadIdx.x;          // 0..131071
  int row = gid >> 2;
  int d0 = (gid & 3) << 5;
  const float* xr = x + (size_t)row * 128 + d0;
  float xv[32], qv[32];
#pragma unroll
  for (int i = 0; i < 32; ++i) { xv[i] = xr[i]; qv[i] = 0.f; }
  double cl = 0.0;
  for (int k = 0; k < 32; ++k) {
    int c = (int)idxF[(k << 15) + row];
    const float* qp = cb + ((size_t)k << 17) + ((size_t)c << 7) + d0;
#pragma unroll
    for (int i = 0; i < 32; ++i) {
      float v = qp[i];
      qv[i] = qv[i] + v;                  // fp32 adds in k-order (np order)
      float e = v - xv[i];
      cl += (double)e * (double)e;
    }
  }
  float* op = outQ + (size_t)row * 128 + d0;
#pragma unroll
  for (int i = 0; i < 32; ++i) op[i] = np_ste(xv[i], qv[i]);
  __shared__ double red[256];
  red[threadIdx.x] = cl;
  __syncthreads();
  for (int s = 128; s > 0; s >>= 1) {
    if (threadIdx.x < s) red[threadIdx.x] += red[threadIdx.x + s];
    __syncthreads();
  }
  if (threadIdx.x == 0) partials[blockIdx.x] = red[0];
}

// ---- F: final closs reduction ------------------------------------------------
__global__ __launch_bounds__(256) void closs_final(const double* __restrict__ partials,
                                                   float* __restrict__ out) {
  __shared__ double red[256];
  red[threadIdx.x] = partials[threadIdx.x] + partials[threadIdx.x + 256];
  __syncthreads();
  for (int s = 128; s > 0; s >>= 1) {
    if (threadIdx.x < s) red[threadIdx.x] += red[threadIdx.x + s];
    __syncthreads();
  }
  if (threadIdx.x == 0) out[0] = (float)(red[0] * (0.25 / 4194304.0));
}

extern "C" void kernel_launch(void* const* d_in, const int* in_sizes, int n_in,
                              void* d_out, int out_size, void* d_ws, size_t ws_size,
                              hipStream_t stream) {
  const float* af    = (const float*)d_in[0];
  const float* ctx   = (const float*)d_in[1];
  const float* in_w  = (const float*)d_in[2];
  const float* in_b  = (const float*)d_in[3];
  const float* cb    = (const float*)d_in[4];
  const float* sem_w = (const float*)d_in[5];
  const float* sem_b = (const float*)d_in[6];

  float* out     = (float*)d_out;
  float* outQ    = out;
  float* outIdx  = out + 4194304;
  float* outLoss = out + 5242880;

  float*  ws_bias  = (float*)d_ws;                    // 10240
  float*  ws_x     = ws_bias + 10240;                 // 4194304
  float*  ws_norms = ws_x + 4194304;                  // 32768
  double* ws_part  = (double*)(ws_norms + 32768);     // 512 doubles

  hipLaunchKernelGGL(code_norms_np, dim3(128), dim3(256), 0, stream, cb, ws_norms);
  hipLaunchKernelGGL(xproj_blas, dim3(128), dim3(256), 0, stream, af, in_w, in_b, ws_x);
  hipLaunchKernelGGL(sembias_blas, dim3(5), dim3(256), 0, stream, sem_w, sem_b, ctx,
                     ws_bias);
  hipLaunchKernelGGL(rvq_main, dim3(512), dim3(512), 0, stream, cb, ws_norms,
                     ws_bias, ws_x, outIdx);
  hipLaunchKernelGGL(quant_closs, dim3(512), dim3(256), 0, stream, cb, ws_x,
                     outIdx, outQ, ws_part);
  hipLaunchKernelGGL(closs_final, dim3(1), dim3(256), 0, stream, ws_part, outLoss);
}

// Round 9
// 5232.844 us; speedup vs baseline: 1.7038x; 1.7038x over previous
//
#include <hip/hip_runtime.h>

// RVQ encoder — bit-exact emulation of the harness numpy reference under the
// BLAS hypothesis: einsums evaluated via OpenBLAS sgemm (k-serial FMA chains,
// Q=384 panel splits), np.sum via scalar pairwise 8-accumulator blocks.
//  * E(d2) (K=128):   acc = fmaf(r[k], c[k], acc), k ascending, single chain
//  * x-proj (K=512):  (chain(0:384) + chain(384:512)) + in_b
//  * sem-bias(K=4096):((ch0+ch1)+...)+ch10 (10x384+256) + sem_b
//  * A,C:             numpy pairwise 8-acc, ((s0+s1)+(s2+s3))+((s4+s5)+(s6+s7))
//  * d2 = (A - 2f*E) + C ; argmin = first minimum (lowest index on ties)
//
// R9 change: keep R7's scalar-broadcast codebook transport (SMEM; R8 proved
// the vector path is L1-BW-bound at 33 MB/CU/k-step), but amortize it over
// 2x rows and 2x resident waves. rvq_main: 1024 thr / 16 waves / 128 rows
// per WG, 256 WGs = exactly 1 WG/CU. Wave w scans codes [w*64,+64); lane
// handles rows {lane, lane+64}: wave-uniform code loads (SGPR broadcast)
// now feed 64 FMAs per 8 loads (2x R7). Per-CU SMEM halves; VALU floor
// unchanged (55 us/k-step); occupancy 16 waves/CU at the VGPR=64 bin
// ((1024,4)). biasS staging dropped (direct biasg reads, 128 floats
// broadcast) to fit LDS ~84 KB. Exact numerics unchanged: E per (row,code)
// is one k-ascending fmaf chain; per-row merge ascending code over 16
// waves; first-minimum tie rule; bias/A/subtract orders identical.
//
// ws: biasg f32[10240] | x f32[4194304] | norms f32[32768] | part f64[512]
// d_out (f32): quantized[4194304] | indices-as-f32[1048576] | closs[1]

// ---- np-exact helpers --------------------------------------------------------

__device__ __forceinline__ float np_add_scaled(float r, float b) {
#pragma clang fp contract(off)
  float t = 0.1f * b;
  return r + t;
}

__device__ __forceinline__ float np_ste(float x, float q) {
#pragma clang fp contract(off)
  float t = q - x;
  return x + t;
}

// numpy pairwise 8-acc sum of squares over 128 elems read as float4[32]
__device__ __forceinline__ float np_A_from(const float4* __restrict__ r4p) {
  float A;
  {
#pragma clang fp contract(off)
    float4 u = r4p[0], v = r4p[1];
    float s0 = u.x * u.x, s1 = u.y * u.y, s2 = u.z * u.z, s3 = u.w * u.w;
    float s4 = v.x * v.x, s5 = v.y * v.y, s6 = v.z * v.z, s7 = v.w * v.w;
#pragma unroll
    for (int t = 1; t < 16; ++t) {
      u = r4p[2 * t]; v = r4p[2 * t + 1];
      s0 += u.x * u.x; s1 += u.y * u.y; s2 += u.z * u.z; s3 += u.w * u.w;
      s4 += v.x * v.x; s5 += v.y * v.y; s6 += v.z * v.z; s7 += v.w * v.w;
    }
    A = ((s0 + s1) + (s2 + s3)) + ((s4 + s5) + (s6 + s7));
  }
  return A;
}

// ---- A: per-code norms (np pairwise 8-acc, streaming) ------------------------
__global__ __launch_bounds__(256) void code_norms_np(const float* __restrict__ cb,
                                                     float* __restrict__ norms) {
  int i = blockIdx.x * 256 + threadIdx.x;            // k*1024+c
  norms[i] = np_A_from((const float4*)(cb + (size_t)i * 128));
}

// ---- B: x = af @ in_w^T + in_b via sgemm semantics (K=512 -> 384+128) --------
__global__ __launch_bounds__(256, 2) void xproj_blas(const float* __restrict__ af,
                                                     const float* __restrict__ in_w,
                                                     const float* __restrict__ in_b,
                                                     float* __restrict__ x) {
  int row = blockIdx.x * 256 + threadIdx.x;          // 0..32767
  const float* ar = af + (size_t)row * 512;
  for (int oc = 0; oc < 8; ++oc) {                   // 16 outputs per group
    float accA[16], accB[16];
#pragma unroll
    for (int o = 0; o < 16; ++o) { accA[o] = 0.f; accB[o] = 0.f; }
    for (int kc = 0; kc < 8; ++kc) {                 // 64-element k chunks
      float a[64];
      const float4* ap = (const float4*)(ar + kc * 64);
#pragma unroll
      for (int i = 0; i < 16; ++i) {
        float4 v = ap[i];
        a[4 * i] = v.x; a[4 * i + 1] = v.y; a[4 * i + 2] = v.z; a[4 * i + 3] = v.w;
      }
      if (kc < 6) {                                  // k = 0..383 -> panel A
#pragma unroll
        for (int o = 0; o < 16; ++o) {
          const float* wr = in_w + (size_t)(oc * 16 + o) * 512 + kc * 64;
          float acc = accA[o];
#pragma unroll
          for (int m = 0; m < 64; ++m) acc = fmaf(a[m], wr[m], acc);
          accA[o] = acc;
        }
      } else {                                       // k = 384..511 -> panel B
#pragma unroll
        for (int o = 0; o < 16; ++o) {
          const float* wr = in_w + (size_t)(oc * 16 + o) * 512 + kc * 64;
          float acc = accB[o];
#pragma unroll
          for (int m = 0; m < 64; ++m) acc = fmaf(a[m], wr[m], acc);
          accB[o] = acc;
        }
      }
    }
    {
#pragma clang fp contract(off)
#pragma unroll
      for (int o = 0; o < 16; ++o) {
        float E = accA[o] + accB[o];                 // panel junction add
        x[(size_t)row * 128 + oc * 16 + o] = E + in_b[oc * 16 + o];
      }
    }
  }
}

// ---- C: sem_bias via sgemm semantics (K=4096 -> 10x384 + 256 panels) ---------
__global__ __launch_bounds__(256) void sembias_blas(const float* __restrict__ sem_w,
                                                    const float* __restrict__ sem_b,
                                                    const float* __restrict__ ctx,
                                                    float* __restrict__ biasg) {
  int tid = blockIdx.x * 256 + threadIdx.x;          // 0..1279 = k*128+d
  if (tid >= 1280) return;
  int k = tid >> 7, d = tid & 127;
  const float* w = sem_w + (size_t)tid * 4096;
  float val[8];
  for (int j = 0; j < 11; ++j) {                     // sgemm k-panels
    int p0 = j * 384;
    int len = (j < 10) ? 384 : 256;                  // 10*384 + 256 = 4096
    float acc[8] = {0.f, 0.f, 0.f, 0.f, 0.f, 0.f, 0.f, 0.f};
    for (int i = 0; i < len; ++i) {
      float wv = w[p0 + i];
#pragma unroll
      for (int b = 0; b < 8; ++b)
        acc[b] = fmaf(wv, ctx[(size_t)b * 4096 + p0 + i], acc[b]);
    }
    {
#pragma clang fp contract(off)
      if (j == 0) {
#pragma unroll
        for (int b = 0; b < 8; ++b) val[b] = acc[b];
      } else {
#pragma unroll
        for (int b = 0; b < 8; ++b) val[b] = val[b] + acc[b];
      }
    }
  }
  {
#pragma clang fp contract(off)
#pragma unroll
    for (int b = 0; b < 8; ++b)
      biasg[((size_t)k * 8 + b) * 128 + d] = val[b] + sem_b[k * 128 + d];
  }
}

// ---- D: main 32-step loop — r in LDS, 2 rows/lane, scalar codebook -----------
// 1024 threads = 16 waves; 128 rows/WG; 256 WGs (1 WG/CU). Wave w scans
// codes [w*64, +64) in 8 blocks of 8 (wave-uniform addresses -> SGPR
// broadcast). Lane handles rows {lane, lane+64}. Cooperative phases use
// (r0 = tid&127, seg = tid>>7): each thread owns 16 dims of one row.
#define RSTRIDE 132                                   // 128 + 4 pad (16B-aligned)
__global__ __launch_bounds__(1024, 4) void rvq_main(const float* __restrict__ cb,
                                                    const float* __restrict__ norms,
                                                    const float* __restrict__ biasg,
                                                    const float* __restrict__ x,
                                                    float* __restrict__ outIdx) {
  const int tid = threadIdx.x;
  const int lane = tid & 63;
  const int wave = __builtin_amdgcn_readfirstlane(tid >> 6);  // 0..15
  const int wg = blockIdx.x;                          // 0..255
  const int b = wg >> 5;                              // 32 WGs per batch row

  __shared__ float rS[128 * RSTRIDE];                 // 67.6 KB
  __shared__ float candVa[16][64];                    // rows 0..63
  __shared__ int candIa[16][64];
  __shared__ float candVb[16][64];                    // rows 64..127
  __shared__ int candIb[16][64];
  __shared__ int chosen[128];

  const int r0 = tid & 127, seg = tid >> 7;           // 16 dims per thread
  {
    const float4* xp = (const float4*)(x + (size_t)((wg << 7) + r0) * 128 + seg * 16);
    float4* rp = (float4*)(rS + r0 * RSTRIDE + seg * 16);
#pragma unroll
    for (int i = 0; i < 4; ++i) rp[i] = xp[i];
  }
  __syncthreads();

  const int cstart = wave << 6;                       // 64 codes per wave
  const float4* r4pa = (const float4*)(rS + lane * RSTRIDE);
  const float4* r4pb = (const float4*)(rS + (lane + 64) * RSTRIDE);

  for (int k = 0; k < 32; ++k) {
    if (k < 10) {                                     // bias add, np order
      const float* bp = biasg + ((size_t)k * 8 + b) * 128 + seg * 16;
      float* rp = rS + r0 * RSTRIDE + seg * 16;
#pragma unroll
      for (int d = 0; d < 16; ++d) rp[d] = np_add_scaled(rp[d], bp[d]);
      __syncthreads();
    }
    // A for both rows (np pairwise 8-acc)
    float Aa = np_A_from(r4pa);
    float Ab = np_A_from(r4pb);

    const float* cbk = cb + ((size_t)k << 17);
    const float* nk = norms + (k << 10);
    float bestVa = 3.4e38f, bestVb = 3.4e38f;
    int bestIa = cstart, bestIb = cstart;
    for (int blk = 0; blk < 8; ++blk) {               // 8 codes per block
      const int cbase = cstart + (blk << 3);
      const float4* c4 = (const float4*)(cbk + ((size_t)cbase << 7));  // uniform
      float Ea0 = 0.f, Ea1 = 0.f, Ea2 = 0.f, Ea3 = 0.f;
      float Ea4 = 0.f, Ea5 = 0.f, Ea6 = 0.f, Ea7 = 0.f;
      float Eb0 = 0.f, Eb1 = 0.f, Eb2 = 0.f, Eb3 = 0.f;
      float Eb4 = 0.f, Eb5 = 0.f, Eb6 = 0.f, Eb7 = 0.f;
      for (int kk = 0; kk < 32; ++kk) {               // k4 chunks, ascending
        float4 ra = r4pa[kk];
        float4 rb = r4pb[kk];
        float4 q0 = c4[kk];                           // code j at +j*32 float4s
        float4 q1 = c4[kk + 32];
        float4 q2 = c4[kk + 64];
        float4 q3 = c4[kk + 96];
        float4 q4 = c4[kk + 128];
        float4 q5 = c4[kk + 160];
        float4 q6 = c4[kk + 192];
        float4 q7 = c4[kk + 224];
        Ea0 = fmaf(ra.x, q0.x, Ea0); Ea0 = fmaf(ra.y, q0.y, Ea0);
        Ea0 = fmaf(ra.z, q0.z, Ea0); Ea0 = fmaf(ra.w, q0.w, Ea0);
        Eb0 = fmaf(rb.x, q0.x, Eb0); Eb0 = fmaf(rb.y, q0.y, Eb0);
        Eb0 = fmaf(rb.z, q0.z, Eb0); Eb0 = fmaf(rb.w, q0.w, Eb0);
        Ea1 = fmaf(ra.x, q1.x, Ea1); Ea1 = fmaf(ra.y, q1.y, Ea1);
        Ea1 = fmaf(ra.z, q1.z, Ea1); Ea1 = fmaf(ra.w, q1.w, Ea1);
        Eb1 = fmaf(rb.x, q1.x, Eb1); Eb1 = fmaf(rb.y, q1.y, Eb1);
        Eb1 = fmaf(rb.z, q1.z, Eb1); Eb1 = fmaf(rb.w, q1.w, Eb1);
        Ea2 = fmaf(ra.x, q2.x, Ea2); Ea2 = fmaf(ra.y, q2.y, Ea2);
        Ea2 = fmaf(ra.z, q2.z, Ea2); Ea2 = fmaf(ra.w, q2.w, Ea2);
        Eb2 = fmaf(rb.x, q2.x, Eb2); Eb2 = fmaf(rb.y, q2.y, Eb2);
        Eb2 = fmaf(rb.z, q2.z, Eb2); Eb2 = fmaf(rb.w, q2.w, Eb2);
        Ea3 = fmaf(ra.x, q3.x, Ea3); Ea3 = fmaf(ra.y, q3.y, Ea3);
        Ea3 = fmaf(ra.z, q3.z, Ea3); Ea3 = fmaf(ra.w, q3.w, Ea3);
        Eb3 = fmaf(rb.x, q3.x, Eb3); Eb3 = fmaf(rb.y, q3.y, Eb3);
        Eb3 = fmaf(rb.z, q3.z, Eb3); Eb3 = fmaf(rb.w, q3.w, Eb3);
        Ea4 = fmaf(ra.x, q4.x, Ea4); Ea4 = fmaf(ra.y, q4.y, Ea4);
        Ea4 = fmaf(ra.z, q4.z, Ea4); Ea4 = fmaf(ra.w, q4.w, Ea4);
        Eb4 = fmaf(rb.x, q4.x, Eb4); Eb4 = fmaf(rb.y, q4.y, Eb4);
        Eb4 = fmaf(rb.z, q4.z, Eb4); Eb4 = fmaf(rb.w, q4.w, Eb4);
        Ea5 = fmaf(ra.x, q5.x, Ea5); Ea5 = fmaf(ra.y, q5.y, Ea5);
        Ea5 = fmaf(ra.z, q5.z, Ea5); Ea5 = fmaf(ra.w, q5.w, Ea5);
        Eb5 = fmaf(rb.x, q5.x, Eb5); Eb5 = fmaf(rb.y, q5.y, Eb5);
        Eb5 = fmaf(rb.z, q5.z, Eb5); Eb5 = fmaf(rb.w, q5.w, Eb5);
        Ea6 = fmaf(ra.x, q6.x, Ea6); Ea6 = fmaf(ra.y, q6.y, Ea6);
        Ea6 = fmaf(ra.z, q6.z, Ea6); Ea6 = fmaf(ra.w, q6.w, Ea6);
        Eb6 = fmaf(rb.x, q6.x, Eb6); Eb6 = fmaf(rb.y, q6.y, Eb6);
        Eb6 = fmaf(rb.z, q6.z, Eb6); Eb6 = fmaf(rb.w, q6.w, Eb6);
        Ea7 = fmaf(ra.x, q7.x, Ea7); Ea7 = fmaf(ra.y, q7.y, Ea7);
        Ea7 = fmaf(ra.z, q7.z, Ea7); Ea7 = fmaf(ra.w, q7.w, Ea7);
        Eb7 = fmaf(rb.x, q7.x, Eb7); Eb7 = fmaf(rb.y, q7.y, Eb7);
        Eb7 = fmaf(rb.z, q7.z, Eb7); Eb7 = fmaf(rb.w, q7.w, Eb7);
      }
      {                                               // exact e, np_d2_blas form
#pragma clang fp contract(off)
        float e;
        e = (Aa - 2.0f * Ea0) + nk[cbase + 0];
        if (e < bestVa) { bestVa = e; bestIa = cbase + 0; }
        e = (Aa - 2.0f * Ea1) + nk[cbase + 1];
        if (e < bestVa) { bestVa = e; bestIa = cbase + 1; }
        e = (Aa - 2.0f * Ea2) + nk[cbase + 2];
        if (e < bestVa) { bestVa = e; bestIa = cbase + 2; }
        e = (Aa - 2.0f * Ea3) + nk[cbase + 3];
        if (e < bestVa) { bestVa = e; bestIa = cbase + 3; }
        e = (Aa - 2.0f * Ea4) + nk[cbase + 4];
        if (e < bestVa) { bestVa = e; bestIa = cbase + 4; }
        e = (Aa - 2.0f * Ea5) + nk[cbase + 5];
        if (e < bestVa) { bestVa = e; bestIa = cbase + 5; }
        e = (Aa - 2.0f * Ea6) + nk[cbase + 6];
        if (e < bestVa) { bestVa = e; bestIa = cbase + 6; }
        e = (Aa - 2.0f * Ea7) + nk[cbase + 7];
        if (e < bestVa) { bestVa = e; bestIa = cbase + 7; }
        e = (Ab - 2.0f * Eb0) + nk[cbase + 0];
        if (e < bestVb) { bestVb = e; bestIb = cbase + 0; }
        e = (Ab - 2.0f * Eb1) + nk[cbase + 1];
        if (e < bestVb) { bestVb = e; bestIb = cbase + 1; }
        e = (Ab - 2.0f * Eb2) + nk[cbase + 2];
        if (e < bestVb) { bestVb = e; bestIb = cbase + 2; }
        e = (Ab - 2.0f * Eb3) + nk[cbase + 3];
        if (e < bestVb) { bestVb = e; bestIb = cbase + 3; }
        e = (Ab - 2.0f * Eb4) + nk[cbase + 4];
        if (e < bestVb) { bestVb = e; bestIb = cbase + 4; }
        e = (Ab - 2.0f * Eb5) + nk[cbase + 5];
        if (e < bestVb) { bestVb = e; bestIb = cbase + 5; }
        e = (Ab - 2.0f * Eb6) + nk[cbase + 6];
        if (e < bestVb) { bestVb = e; bestIb = cbase + 6; }
        e = (Ab - 2.0f * Eb7) + nk[cbase + 7];
        if (e < bestVb) { bestVb = e; bestIb = cbase + 7; }
      }
    }
    candVa[wave][lane] = bestVa;
    candIa[wave][lane] = bestIa;
    candVb[wave][lane] = bestVb;
    candIb[wave][lane] = bestIb;
    __syncthreads();
    if (tid < 128) {                                  // merge for row tid
      const int rr = tid;
      const int slot = rr >> 6;                       // 0: rows 0-63; 1: 64-127
      const int src = rr & 63;
      float mv = 3.4e38f;
      int mi = 0;
#pragma unroll
      for (int w = 0; w < 16; ++w) {                  // ascending code ranges
        float v = slot ? candVb[w][src] : candVa[w][src];
        int ci = slot ? candIb[w][src] : candIa[w][src];
        if (v < mv || (v == mv && ci < mi)) { mv = v; mi = ci; }
      }
      chosen[rr] = mi;
      outIdx[(k << 15) + (wg << 7) + rr] = (float)mi;
    }
    __syncthreads();
    {                                                 // subtract, exact single sub
      const float* q = cbk + ((size_t)chosen[r0] << 7) + seg * 16;
      float* rp = rS + r0 * RSTRIDE + seg * 16;
#pragma unroll
      for (int d = 0; d < 16; ++d) rp[d] = rp[d] - q[d];
    }
    __syncthreads();
  }
}

// ---- E: quantized (fp32 k-order accumulate + STE) + closs partials -----------
__global__ __launch_bounds__(256) void quant_closs(const float* __restrict__ cb,
                                                   const float* __restrict__ x,
                                                   const float* __restrict__ idxF,
                                                   float* __restrict__ outQ,
                                                   double* __restrict__ partials) {
  int gid = blockIdx.x * 256 + threadIdx.x;          // 0..131071
  int row = gid >> 2;
  int d0 = (gid & 3) << 5;
  const float* xr = x + (size_t)row * 128 + d0;
  float xv[32], qv[32];
#pragma unroll
  for (int i = 0; i < 32; ++i) { xv[i] = xr[i]; qv[i] = 0.f; }
  double cl = 0.0;
  for (int k = 0; k < 32; ++k) {
    int c = (int)idxF[(k << 15) + row];
    const float* qp = cb + ((size_t)k << 17) + ((size_t)c << 7) + d0;
#pragma unroll
    for (int i = 0; i < 32; ++i) {
      float v = qp[i];
      qv[i] = qv[i] + v;                  // fp32 adds in k-order (np order)
      float e = v - xv[i];
      cl += (double)e * (double)e;
    }
  }
  float* op = outQ + (size_t)row * 128 + d0;
#pragma unroll
  for (int i = 0; i < 32; ++i) op[i] = np_ste(xv[i], qv[i]);
  __shared__ double red[256];
  red[threadIdx.x] = cl;
  __syncthreads();
  for (int s = 128; s > 0; s >>= 1) {
    if (threadIdx.x < s) red[threadIdx.x] += red[threadIdx.x + s];
    __syncthreads();
  }
  if (threadIdx.x == 0) partials[blockIdx.x] = red[0];
}

// ---- F: final closs reduction ------------------------------------------------
__global__ __launch_bounds__(256) void closs_final(const double* __restrict__ partials,
                                                   float* __restrict__ out) {
  __shared__ double red[256];
  red[threadIdx.x] = partials[threadIdx.x] + partials[threadIdx.x + 256];
  __syncthreads();
  for (int s = 128; s > 0; s >>= 1) {
    if (threadIdx.x < s) red[threadIdx.x] += red[threadIdx.x + s];
    __syncthreads();
  }
  if (threadIdx.x == 0) out[0] = (float)(red[0] * (0.25 / 4194304.0));
}

extern "C" void kernel_launch(void* const* d_in, const int* in_sizes, int n_in,
                              void* d_out, int out_size, void* d_ws, size_t ws_size,
                              hipStream_t stream) {
  const float* af    = (const float*)d_in[0];
  const float* ctx   = (const float*)d_in[1];
  const float* in_w  = (const float*)d_in[2];
  const float* in_b  = (const float*)d_in[3];
  const float* cb    = (const float*)d_in[4];
  const float* sem_w = (const float*)d_in[5];
  const float* sem_b = (const float*)d_in[6];

  float* out     = (float*)d_out;
  float* outQ    = out;
  float* outIdx  = out + 4194304;
  float* outLoss = out + 5242880;

  float*  ws_bias  = (float*)d_ws;                    // 10240
  float*  ws_x     = ws_bias + 10240;                 // 4194304
  float*  ws_norms = ws_x + 4194304;                  // 32768
  double* ws_part  = (double*)(ws_norms + 32768);     // 512 doubles

  hipLaunchKernelGGL(code_norms_np, dim3(128), dim3(256), 0, stream, cb, ws_norms);
  hipLaunchKernelGGL(xproj_blas, dim3(128), dim3(256), 0, stream, af, in_w, in_b, ws_x);
  hipLaunchKernelGGL(sembias_blas, dim3(5), dim3(256), 0, stream, sem_w, sem_b, ctx,
                     ws_bias);
  hipLaunchKernelGGL(rvq_main, dim3(256), dim3(1024), 0, stream, cb, ws_norms,
                     ws_bias, ws_x, outIdx);
  hipLaunchKernelGGL(quant_closs, dim3(512), dim3(256), 0, stream, cb, ws_x,
                     outIdx, outQ, ws_part);
  hipLaunchKernelGGL(closs_final, dim3(1), dim3(256), 0, stream, ws_part, outLoss);
}